// Round 1
// baseline (509.867 us; speedup 1.0000x reference)
//
#include <hip/hip_runtime.h>

typedef unsigned short u16;
typedef unsigned int   u32;
typedef __attribute__((ext_vector_type(4))) float  f32x4;
typedef __attribute__((ext_vector_type(8))) __bf16 bf16x8;

// ---------------- constants ----------------
#define BATCH 8
#define SEQ   2048
#define DMODEL 1024
#define DK    512
#define DV    512
// softmax scale = 1/sqrt(512)
#define SCALE 0.044194173824159216f

__device__ __forceinline__ u16 f2bf(float f) {
  u32 u = __float_as_uint(f);
  return (u16)((u + 0x7fffu + ((u >> 16) & 1u)) >> 16);
}

// mask dtype mode: 0 = int32, 1 = uint8, 2 = float32
__device__ __forceinline__ bool read_mask(const void* p, int idx, int mode) {
  if (mode == 1) return ((const unsigned char*)p)[idx] != 0;
  if (mode == 2) return ((const float*)p)[idx] != 0.0f;
  return ((const int*)p)[idx] != 0;
}

// ---------------- kernel 0: detect mask dtype ----------------
__global__ void detect_mode(const int* __restrict__ qp, int* __restrict__ flag) {
  __shared__ int f;
  if (threadIdx.x == 0) f = 0;
  __syncthreads();
  int local = 0;
  // 4096 ints == 16KB == exactly the uint8-size of one mask; safe for all dtypes
  for (int i = threadIdx.x; i < 4096; i += 256) {
    int v = qp[i];
    if (v == 0x3F800000) local |= 2;                      // 1.0f pattern -> float32
    else if (v != 0 && v != 1 && v != -1) local |= 1;     // packed bytes -> uint8
  }
  if (local) atomicOr(&f, local);
  __syncthreads();
  if (threadIdx.x == 0) {
    int m = 0;
    if (f & 2) m = 2; else if (f & 1) m = 1;
    *flag = m;
  }
}

// ---------------- kernel 1: W [1024][512] f32 -> Wt [512][1024] bf16 ----------------
__global__ __launch_bounds__(256) void wt_transpose(const float* __restrict__ W0,
                                                    const float* __restrict__ W1,
                                                    const float* __restrict__ W2,
                                                    u16* __restrict__ dst) {
  const float* W = (blockIdx.z == 0) ? W0 : (blockIdx.z == 1) ? W1 : W2;
  u16* out = dst + (size_t)blockIdx.z * (DK * DMODEL);
  __shared__ float T[32][33];
  int k0 = blockIdx.x * 32, n0 = blockIdx.y * 32;
  int tx = threadIdx.x, ty = threadIdx.y; // (32,8)
#pragma unroll
  for (int i = 0; i < 4; ++i) {
    int r = ty + i * 8;
    T[r][tx] = W[(size_t)(k0 + r) * DK + n0 + tx];
  }
  __syncthreads();
#pragma unroll
  for (int i = 0; i < 4; ++i) {
    int r = ty + i * 8;
    out[(size_t)(n0 + r) * DMODEL + k0 + tx] = f2bf(T[tx][r]);
  }
}

// ---------------- kernel 2: projections, NT MFMA GEMM ----------------
// C[16384][512] = A[16384][1024](f32) * Wt[512][1024](bf16)^T ; out bf16
// grid (4 n-tiles, 128 m-tiles, 3 gemms), block 256 (4 waves, 2x2 of 64x64)
__global__ __launch_bounds__(256) void proj_gemm(const float* __restrict__ sq,
                                                 const float* __restrict__ skv,
                                                 const u16* __restrict__ Wts,
                                                 u16* __restrict__ outs) {
  int z = blockIdx.z;
  const float* A = (z == 0) ? sq : skv;
  const u16* Wt = Wts + (size_t)z * (DK * DMODEL);
  u16* out = outs + (size_t)z * ((size_t)BATCH * SEQ * DK);
  int n0 = blockIdx.x * 128, m0 = blockIdx.y * 128;
  __shared__ __align__(16) u16 As[128 * 40]; // stride 40 (pad 8)
  __shared__ __align__(16) u16 Bs[128 * 40];
  int tid = threadIdx.x, lane = tid & 63, w = tid >> 6;
  int wm = w & 1, wn = w >> 1;
  int l15 = lane & 15, lg = lane >> 4;
  f32x4 acc[4][4];
#pragma unroll
  for (int m = 0; m < 4; ++m)
#pragma unroll
    for (int n = 0; n < 4; ++n) acc[m][n] = (f32x4)0.0f;

  for (int k0 = 0; k0 < DMODEL; k0 += 32) {
    __syncthreads();
    // stage A (f32 -> bf16): 128 rows x 32
#pragma unroll
    for (int t = 0; t < 4; ++t) {
      int idx = t * 256 + tid; int r = idx >> 3, c4 = idx & 7;
      f32x4 v = *(const f32x4*)(A + (size_t)(m0 + r) * DMODEL + k0 + c4 * 4);
      u32* d = (u32*)(As + r * 40 + c4 * 4);
      d[0] = (u32)f2bf(v[0]) | ((u32)f2bf(v[1]) << 16);
      d[1] = (u32)f2bf(v[2]) | ((u32)f2bf(v[3]) << 16);
    }
    // stage B (bf16): 128 rows x 32
#pragma unroll
    for (int t = 0; t < 2; ++t) {
      int idx = t * 256 + tid; int r = idx >> 2, c = idx & 3;
      uint4 v = *(const uint4*)(Wt + (size_t)(n0 + r) * DMODEL + k0 + c * 8);
      *(uint4*)(Bs + r * 40 + c * 8) = v;
    }
    __syncthreads();
    bf16x8 af[4], bfv[4];
#pragma unroll
    for (int m = 0; m < 4; ++m)
      af[m] = *(const bf16x8*)(As + (wm * 64 + m * 16 + l15) * 40 + lg * 8);
#pragma unroll
    for (int n = 0; n < 4; ++n)
      bfv[n] = *(const bf16x8*)(Bs + (wn * 64 + n * 16 + l15) * 40 + lg * 8);
#pragma unroll
    for (int m = 0; m < 4; ++m)
#pragma unroll
      for (int n = 0; n < 4; ++n)
        acc[m][n] = __builtin_amdgcn_mfma_f32_16x16x32_bf16(af[m], bfv[n], acc[m][n], 0, 0, 0);
  }
  // epilogue: C/D layout col=lane&15, row=(lane>>4)*4+r
#pragma unroll
  for (int m = 0; m < 4; ++m)
#pragma unroll
    for (int n = 0; n < 4; ++n) {
      int col = n0 + wn * 64 + n * 16 + l15;
#pragma unroll
      for (int r = 0; r < 4; ++r) {
        int row = m0 + wm * 64 + m * 16 + lg * 4 + r;
        out[(size_t)row * DK + col] = f2bf(acc[m][n][r]);
      }
    }
}

// ---------------- kernel 3: V [16384][512] -> Vt [8][512][2048] (bf16) ----------------
__global__ __launch_bounds__(256) void v_transpose(const u16* __restrict__ Vb,
                                                   u16* __restrict__ Vt) {
  __shared__ __align__(16) u16 T[64 * 66]; // stride 66
  int d0 = blockIdx.x * 64;
  int srow = blockIdx.y * 64;
  int b = srow >> 11;
  int sl = srow & 2047;
  int tid = threadIdx.x;
#pragma unroll
  for (int t = 0; t < 2; ++t) {
    int idx = t * 256 + tid; int r = idx >> 3, c8 = idx & 7;
    uint4 v = *(const uint4*)(Vb + (size_t)(srow + r) * DV + d0 + c8 * 8);
    u32* d = (u32*)(T + r * 66 + c8 * 8);
    d[0] = v.x; d[1] = v.y; d[2] = v.z; d[3] = v.w;
  }
  __syncthreads();
#pragma unroll
  for (int t = 0; t < 2; ++t) {
    int idx = t * 256 + tid; int dr = idx >> 3, c8 = idx & 7;
    u16 tmp[8] __attribute__((aligned(16)));
#pragma unroll
    for (int jj = 0; jj < 8; ++jj) tmp[jj] = T[(c8 * 8 + jj) * 66 + dr];
    *(uint4*)(Vt + (size_t)b * (DV * SEQ) + (size_t)(d0 + dr) * SEQ + sl + c8 * 8) =
        *(const uint4*)tmp;
  }
}

// ---------------- kernel 4: flash attention ----------------
// Tq=32/block, Tk=64; 4 waves: wave w computes S[32q x keys w*16..w*16+15],
// owns dv slices {w*64..w*64+63} in each 256-dv chunk.
#define QOFF 0        // [32][264] bf16 = 16896 B
#define KOFF 16896    // [64][264] bf16 = 33792 B
#define SOFF 50688    // [32][68]  f32  =  8704 B
#define VOFF 0        // [256][72] bf16 = 36864 B (unions with Q/K/S; barrier-protected)
#define POFF 59392    // [32][72]  bf16 =  4608 B
#define MOFF 64000
#define LOFF 64128
#define AOFF 64256
#define SMEM_BYTES 64384

__global__ __launch_bounds__(256, 2) void attn_kernel(
    const u16* __restrict__ Qb, const u16* __restrict__ Kb,
    const u16* __restrict__ Vt, const void* __restrict__ qpad,
    const void* __restrict__ kvpad, const int* __restrict__ flag,
    float* __restrict__ out) {
  __shared__ __align__(16) char smem[SMEM_BYTES];
  int tid = threadIdx.x;
  int lane = tid & 63, w = tid >> 6;
  int l15 = lane & 15, lg = lane >> 4;
  int bi = blockIdx.x;
  int b = bi & 7, j = bi >> 3;
  int qt = (j < 32) ? j : 95 - j;   // pair cheap+expensive q-tiles per CU
  int q0 = qt * 32;
  int mode = *flag;

  float* mld = (float*)(smem + MOFF);
  float* lld = (float*)(smem + LOFF);
  float* ald = (float*)(smem + AOFF);
  if (tid < 32) { mld[tid] = -1e38f; lld[tid] = 0.0f; }

  f32x4 o[2][8];
#pragma unroll
  for (int m = 0; m < 2; ++m)
#pragma unroll
    for (int n = 0; n < 8; ++n) o[m][n] = (f32x4)0.0f;

  int nkt = (q0 + 95) >> 6;

  for (int kt = 0; kt < nkt; ++kt) {
    int k0 = kt * 64;
    f32x4 sacc[2];
    sacc[0] = (f32x4)0.0f; sacc[1] = (f32x4)0.0f;

    // ---- S = Q K^T over d in 2 chunks of 256 ----
#pragma unroll
    for (int dc = 0; dc < 2; ++dc) {
      __syncthreads(); // prior readers of this LDS region are done
#pragma unroll
      for (int t = 0; t < 4; ++t) { // Q chunk 32x256
        int idx = t * 256 + tid; int r = idx >> 5, c8 = idx & 31;
        uint4 v = *(const uint4*)(Qb + (size_t)(b * SEQ + q0 + r) * DK + dc * 256 + c8 * 8);
        *(uint4*)(smem + QOFF + (r * 264 + c8 * 8) * 2) = v;
      }
#pragma unroll
      for (int t = 0; t < 8; ++t) { // K chunk 64x256
        int idx = t * 256 + tid; int r = idx >> 5, c8 = idx & 31;
        uint4 v = *(const uint4*)(Kb + (size_t)(b * SEQ + k0 + r) * DK + dc * 256 + c8 * 8);
        *(uint4*)(smem + KOFF + (r * 264 + c8 * 8) * 2) = v;
      }
      __syncthreads();
#pragma unroll
      for (int ks = 0; ks < 8; ++ks) {
        bf16x8 bk = *(const bf16x8*)(smem + KOFF + ((w * 16 + l15) * 264 + ks * 32 + lg * 8) * 2);
        bf16x8 a0 = *(const bf16x8*)(smem + QOFF + ((l15) * 264 + ks * 32 + lg * 8) * 2);
        bf16x8 a1 = *(const bf16x8*)(smem + QOFF + ((16 + l15) * 264 + ks * 32 + lg * 8) * 2);
        sacc[0] = __builtin_amdgcn_mfma_f32_16x16x32_bf16(a0, bk, sacc[0], 0, 0, 0);
        sacc[1] = __builtin_amdgcn_mfma_f32_16x16x32_bf16(a1, bk, sacc[1], 0, 0, 0);
      }
    }

    // ---- scale + mask, write S to LDS ----
    {
      int key = k0 + w * 16 + l15;
      bool kv = read_mask(kvpad, b * SEQ + key, mode);
#pragma unroll
      for (int m = 0; m < 2; ++m)
#pragma unroll
        for (int r = 0; r < 4; ++r) {
          int qg = q0 + m * 16 + lg * 4 + r;
          float s = sacc[m][r] * SCALE;
          if (kv || key > qg) s = -__builtin_inff();
          ((float*)(smem + SOFF))[(m * 16 + lg * 4 + r) * 68 + w * 16 + l15] = s;
        }
    }
    __syncthreads();

    // ---- online softmax: 8 threads per q-row ----
    {
      int row = tid >> 3, g = tid & 7;
      const float* Sp = (const float*)(smem + SOFF) + row * 68 + g * 8;
      f32x4 sa = *(const f32x4*)Sp;
      f32x4 sb = *(const f32x4*)(Sp + 4);
      float tm = fmaxf(fmaxf(fmaxf(sa[0], sa[1]), fmaxf(sa[2], sa[3])),
                       fmaxf(fmaxf(sb[0], sb[1]), fmaxf(sb[2], sb[3])));
      tm = fmaxf(tm, __shfl_xor(tm, 1));
      tm = fmaxf(tm, __shfl_xor(tm, 2));
      tm = fmaxf(tm, __shfl_xor(tm, 4));
      float mo = mld[row];
      float mn = fmaxf(mo, fmaxf(tm, -1e38f)); // clamp: fully-masked rows stay finite
      float al = __expf(mo - mn);
      float p[8];
      p[0] = __expf(sa[0] - mn); p[1] = __expf(sa[1] - mn);
      p[2] = __expf(sa[2] - mn); p[3] = __expf(sa[3] - mn);
      p[4] = __expf(sb[0] - mn); p[5] = __expf(sb[1] - mn);
      p[6] = __expf(sb[2] - mn); p[7] = __expf(sb[3] - mn);
      float ps = p[0] + p[1] + p[2] + p[3] + p[4] + p[5] + p[6] + p[7];
      ps += __shfl_xor(ps, 1);
      ps += __shfl_xor(ps, 2);
      ps += __shfl_xor(ps, 4);
      if (g == 0) { mld[row] = mn; lld[row] = lld[row] * al + ps; ald[row] = al; }
      uint4 pk;
      pk.x = (u32)f2bf(p[0]) | ((u32)f2bf(p[1]) << 16);
      pk.y = (u32)f2bf(p[2]) | ((u32)f2bf(p[3]) << 16);
      pk.z = (u32)f2bf(p[4]) | ((u32)f2bf(p[5]) << 16);
      pk.w = (u32)f2bf(p[6]) | ((u32)f2bf(p[7]) << 16);
      *(uint4*)(smem + POFF + (row * 72 + g * 8) * 2) = pk;
    }
    __syncthreads(); // P + stats visible; S region now dead -> V may overwrite

    // ---- rescale O ----
    {
      float arow[2][4];
#pragma unroll
      for (int m = 0; m < 2; ++m)
#pragma unroll
        for (int r = 0; r < 4; ++r) arow[m][r] = ald[m * 16 + lg * 4 + r];
#pragma unroll
      for (int m = 0; m < 2; ++m)
#pragma unroll
        for (int n = 0; n < 8; ++n)
#pragma unroll
          for (int r = 0; r < 4; ++r) o[m][n][r] *= arow[m][r];
    }

    // ---- O += P V, dv in 2 chunks of 256 ----
#pragma unroll
    for (int c = 0; c < 2; ++c) {
#pragma unroll
      for (int t = 0; t < 8; ++t) { // stage Vt chunk [256 dv][64 keys]
        int idx = t * 256 + tid; int r = idx >> 3, cc = idx & 7;
        uint4 v = *(const uint4*)(Vt + (size_t)b * (DV * SEQ) +
                                  (size_t)(c * 256 + r) * SEQ + k0 + cc * 8);
        *(uint4*)(smem + VOFF + (r * 72 + cc * 8) * 2) = v;
      }
      __syncthreads();
#pragma unroll
      for (int ks = 0; ks < 2; ++ks) {
        bf16x8 pa0 = *(const bf16x8*)(smem + POFF + ((l15) * 72 + ks * 32 + lg * 8) * 2);
        bf16x8 pa1 = *(const bf16x8*)(smem + POFF + ((16 + l15) * 72 + ks * 32 + lg * 8) * 2);
#pragma unroll
        for (int n = 0; n < 4; ++n) {
          bf16x8 bv = *(const bf16x8*)(smem + VOFF +
                                       ((w * 64 + n * 16 + l15) * 72 + ks * 32 + lg * 8) * 2);
          o[0][c * 4 + n] = __builtin_amdgcn_mfma_f32_16x16x32_bf16(pa0, bv, o[0][c * 4 + n], 0, 0, 0);
          o[1][c * 4 + n] = __builtin_amdgcn_mfma_f32_16x16x32_bf16(pa1, bv, o[1][c * 4 + n], 0, 0, 0);
        }
      }
      __syncthreads(); // chunk reads done before region reuse
    }
  }

  // ---- epilogue: out = O / l ; zero fully-masked and padded-q rows ----
  {
    float f[2][4];
#pragma unroll
    for (int m = 0; m < 2; ++m)
#pragma unroll
      for (int r = 0; r < 4; ++r) {
        int ql = m * 16 + lg * 4 + r;
        float l = lld[ql];
        bool qp = read_mask(qpad, b * SEQ + q0 + ql, mode);
        f[m][r] = (l > 0.0f && !qp) ? 1.0f / l : 0.0f;
      }
#pragma unroll
    for (int m = 0; m < 2; ++m)
#pragma unroll
      for (int n = 0; n < 8; ++n) {
        int dv = ((n >> 2) * 256) + w * 64 + (n & 3) * 16 + l15;
#pragma unroll
        for (int r = 0; r < 4; ++r) {
          int ql = m * 16 + lg * 4 + r;
          out[(size_t)(b * SEQ + q0 + ql) * DV + dv] = o[m][n][r] * f[m][r];
        }
      }
  }
}

// ---------------- workspace layout (bytes) ----------------
// Wt (3x bf16 [512][1024]) : 0        .. 3145728
// Qb / Kb / Vb bf16        : 3145728  .. 53477376  (3 x 16777216)
// Vt bf16 [8][512][2048]   : 53477376 .. 70254592
// mask-mode flag (int)     : 70254592 .. 70254596
extern "C" void kernel_launch(void* const* d_in, const int* in_sizes, int n_in,
                              void* d_out, int out_size, void* d_ws, size_t ws_size,
                              hipStream_t stream) {
  const float* sq  = (const float*)d_in[0];
  const float* skv = (const float*)d_in[1];
  const void* qp   = d_in[2];
  const void* kvp  = d_in[3];
  const float* Wq  = (const float*)d_in[4];
  const float* Wk  = (const float*)d_in[5];
  const float* Wv  = (const float*)d_in[6];
  char* ws = (char*)d_ws;

  u16* Wts  = (u16*)ws;
  u16* outs = (u16*)(ws + 3145728);
  u16* Qb = outs;
  u16* Kb = outs + 8388608;
  u16* Vb = outs + 16777216;
  u16* Vt = (u16*)(ws + 53477376);
  int* flag = (int*)(ws + 70254592);

  wt_transpose<<<dim3(32, 16, 3), dim3(32, 8, 1), 0, stream>>>(Wq, Wk, Wv, Wts);
  detect_mode<<<1, 256, 0, stream>>>((const int*)qp, flag);
  proj_gemm<<<dim3(4, 128, 3), dim3(256), 0, stream>>>(sq, skv, Wts, outs);
  v_transpose<<<dim3(8, 256), dim3(256), 0, stream>>>(Vb, Vt);
  attn_kernel<<<dim3(512), dim3(256), 0, stream>>>(Qb, Kb, Vt, qp, kvp, flag,
                                                   (float*)d_out);
}